// Round 4
// baseline (3439.278 us; speedup 1.0000x reference)
//
#include <hip/hip_runtime.h>
#include <hip/hip_bf16.h>

#define NC    64      // channels C
#define NATTR 10      // node attrs
#define KSC   640     // C*NATTR
#define NH    64      // radial MLP hidden
#define NRAD  8       // radial features
#define WN    320     // 5*C tensor-product weights per edge
#define EPB   32      // edges per block in edge kernel
#define MPN   704     // f32 message floats per node: 128 scalar + 576 vector

__device__ __forceinline__ float silu_f(float x) { return x / (1.0f + __expf(-x)); }

// ---------------------------------------------------------------------------
// d_out layout (f32, out_size = N*512):
//   out_s : [0,       N*64 )
//   out_v : [N*64,    N*256)   (N,C,3) row-major
//   sc_s  : [N*256,   N*320)
//   sc_v  : [N*320,   N*512)   (N,C,3) row-major
// The sc region doubles as scratch for the self-linear s,v until sc_kernel
// (launched last) overwrites it:
//   s at N*256 + n*64 + d            (layout [N][64])
//   v at N*320 + n*192 + x*64 + d    (layout [N][3][64])
// ---------------------------------------------------------------------------

// Kernel 1: self linear on node_feats -> f32 s,v scratch in d_out sc region.
__global__ __launch_bounds__(256)
void self_kernel(const float* __restrict__ fs, const float* __restrict__ fv,
                 const float* __restrict__ Wes, const float* __restrict__ Wev,
                 float* __restrict__ out, int N)
{
    __shared__ float s_l[NC];
    __shared__ float v_l[3][NC];
    const int n = blockIdx.x, t = threadIdx.x;

    if (t < NC) s_l[t] = fs[(size_t)n * NC + t];
    for (int i = t; i < NC * 3; i += 256) {
        int c = i / 3, x = i - c * 3;
        v_l[x][c] = fv[(size_t)n * NC * 3 + i];
    }
    __syncthreads();

    const int wave = t >> 6, d = t & 63;
    if (wave == 0) {
        float a = 0.f;
        #pragma unroll 8
        for (int c = 0; c < NC; c++) a += s_l[c] * Wes[c * NC + d];
        out[(size_t)N * 256 + (size_t)n * NC + d] = a * 0.125f;       // 1/sqrt(64)
    } else {
        const int x = wave - 1;
        float a = 0.f;
        #pragma unroll 8
        for (int c = 0; c < NC; c++) a += v_l[x][c] * Wev[c * NC + d];
        out[(size_t)N * 320 + (size_t)n * 192 + x * NC + d] = a * 0.125f;
    }
}

// ---------------------------------------------------------------------------
// Kernel 2 (per receiver-chunk): radial MLP + tensor product + atomic scatter
// into f32 m buffer of (r1-r0) nodes * 704 floats.
// Per-node m layout: [0,64) p1 | [64,128) p2 | 128 + x*192 + {0,64,128} + c
// ---------------------------------------------------------------------------
__global__ __launch_bounds__(256)
void edge_kernel(const float* __restrict__ ef, const float* __restrict__ sh0,
                 const float* __restrict__ sh1,
                 const int* __restrict__ snd, const int* __restrict__ rcv,
                 const float* __restrict__ W1, const float* __restrict__ W2,
                 const float* __restrict__ W3, const float* __restrict__ W4,
                 const float* __restrict__ s_st, const float* __restrict__ v_st,
                 float* __restrict__ m, int E, int r0, int r1)
{
    __shared__ float x_l[EPB][NRAD];
    __shared__ float h_a[EPB][NH];
    __shared__ float h_b[EPB][NH];
    __shared__ float w_l[EPB][WN];
    __shared__ float sh1_l[EPB][3];
    __shared__ float sh0_l[EPB];
    __shared__ int   snd_l[EPB];
    __shared__ int   rcv_l[EPB];

    const int t = threadIdx.x;
    const int e0 = blockIdx.x * EPB;

    for (int i = t; i < EPB * NRAD; i += 256) {
        int e = i >> 3, r = i & 7;
        int eg = e0 + e;
        x_l[e][r] = (eg < E) ? ef[(size_t)eg * NRAD + r] : 0.f;
    }
    if (t < EPB) {
        int eg = e0 + t;
        bool valid = eg < E;
        snd_l[t] = valid ? snd[eg] : 0;
        rcv_l[t] = valid ? rcv[eg] : -2000000000;
        sh0_l[t] = valid ? sh0[eg] : 0.f;
    }
    for (int i = t; i < EPB * 3; i += 256) {
        int e = i / 3, x = i - e * 3;
        int eg = e0 + e;
        sh1_l[e][x] = (eg < E) ? sh1[(size_t)eg * 3 + x] : 0.f;
    }
    __syncthreads();

    for (int i = t; i < EPB * NH; i += 256) {          // 8 -> 64
        int e = i >> 6, j = i & 63;
        float acc = 0.f;
        #pragma unroll
        for (int r = 0; r < NRAD; r++) acc += x_l[e][r] * W1[r * NH + j];
        h_a[e][j] = silu_f(acc * 0.35355339059327373f);  // 1/sqrt(8)
    }
    __syncthreads();
    for (int i = t; i < EPB * NH; i += 256) {          // 64 -> 64
        int e = i >> 6, j = i & 63;
        float acc = 0.f;
        #pragma unroll 8
        for (int c = 0; c < NH; c++) acc += h_a[e][c] * W2[c * NH + j];
        h_b[e][j] = silu_f(acc * 0.125f);
    }
    __syncthreads();
    for (int i = t; i < EPB * NH; i += 256) {          // 64 -> 64
        int e = i >> 6, j = i & 63;
        float acc = 0.f;
        #pragma unroll 8
        for (int c = 0; c < NH; c++) acc += h_b[e][c] * W3[c * NH + j];
        h_a[e][j] = silu_f(acc * 0.125f);
    }
    __syncthreads();
    for (int i = t; i < EPB * WN; i += 256) {          // 64 -> 320
        int e = i / WN, j = i - e * WN;
        float acc = 0.f;
        #pragma unroll 8
        for (int c = 0; c < NH; c++) acc += h_a[e][c] * W4[c * WN + j];
        w_l[e][j] = acc * 0.125f;
    }
    __syncthreads();

    for (int p = 0; p < (EPB * NC) / 256; p++) {
        int i = t + p * 256;
        int e = i >> 6, c = i & 63;
        int r = rcv_l[e];
        if (r < r0 || r >= r1) continue;
        int s = snd_l[e];
        float se = s_st[(size_t)s * NC + c];
        float vx = v_st[(size_t)s * 192 + c];
        float vy = v_st[(size_t)s * 192 + 64 + c];
        float vz = v_st[(size_t)s * 192 + 128 + c];
        float shx = sh1_l[e][0], shy = sh1_l[e][1], shz = sh1_l[e][2];
        float s0 = sh0_l[e];
        float w1v = w_l[e][c],        w2v = w_l[e][64 + c];
        float w3v = w_l[e][128 + c],  w4v = w_l[e][192 + c];
        float w5v = w_l[e][256 + c];

        float p1 = w1v * se * s0;                                   // 0e x 0e
        float dot = vx * shx + vy * shy + vz * shz;
        float p2 = w2v * dot * 0.5773502691896258f;                 // /sqrt(3)
        float w3s = w3v * se;
        float w4s = w4v * s0;
        float cx = vy * shz - vz * shy;
        float cy = vz * shx - vx * shz;
        float cz = vx * shy - vy * shx;
        float w5s = w5v * 0.7071067811865476f;                      // /sqrt(2)

        float* base = m + (size_t)(r - r0) * MPN;
        unsafeAtomicAdd(base + c,        p1);
        unsafeAtomicAdd(base + 64 + c,   p2);
        unsafeAtomicAdd(base + 128 + c,              w3s * shx);
        unsafeAtomicAdd(base + 128 + 64 + c,         w4s * vx);
        unsafeAtomicAdd(base + 128 + 128 + c,        w5s * cx);
        unsafeAtomicAdd(base + 128 + 192 + c,        w3s * shy);
        unsafeAtomicAdd(base + 128 + 192 + 64 + c,   w4s * vy);
        unsafeAtomicAdd(base + 128 + 192 + 128 + c,  w5s * cy);
        unsafeAtomicAdd(base + 128 + 384 + c,        w3s * shz);
        unsafeAtomicAdd(base + 128 + 384 + 64 + c,   w4s * vz);
        unsafeAtomicAdd(base + 128 + 384 + 128 + c,  w5s * cz);
    }
}

// ---------------------------------------------------------------------------
// Kernel 3 (per receiver-chunk): output linear from message buffer.
// ---------------------------------------------------------------------------
__global__ __launch_bounds__(256)
void out_kernel(const float* __restrict__ m,
                const float* __restrict__ Wos, const float* __restrict__ Wov,
                float* __restrict__ out, int N, int r0)
{
    __shared__ float ms_l[128];
    __shared__ float mv_l[3][192];
    const int nl = blockIdx.x, t = threadIdx.x;
    const int n = r0 + nl;
    const float* base = m + (size_t)nl * MPN;

    if (t < 128) ms_l[t] = base[t];
    for (int i = t; i < 576; i += 256) {
        int x = i / 192, k = i - x * 192;
        mv_l[x][k] = base[128 + i];
    }
    __syncthreads();

    const int wave = t >> 6, d = t & 63;
    if (wave == 0) {
        float acc = 0.f;
        #pragma unroll 8
        for (int k = 0; k < 128; k++) acc += ms_l[k] * Wos[k * 64 + d];
        out[(size_t)n * 64 + d] = acc * 0.005524271728019903f;   // 1/(sqrt(128)*16)
    } else {
        const int x = wave - 1;
        float acc = 0.f;
        #pragma unroll 8
        for (int k = 0; k < 192; k++) acc += mv_l[x][k] * Wov[k * 64 + d];
        out[(size_t)N * 64 + (size_t)n * 192 + d * 3 + x] =
            acc * 0.004510527174164819f;                          // 1/(sqrt(192)*16)
    }
}

// ---------------------------------------------------------------------------
// Kernel 4: skip connection (runs last; overwrites the s/v scratch region
// of d_out with the true sc_s / sc_v outputs).
// ---------------------------------------------------------------------------
__global__ __launch_bounds__(256)
void sc_kernel(const float* __restrict__ attrs, const float* __restrict__ fs,
               const float* __restrict__ fv,
               const float* __restrict__ Wss, const float* __restrict__ Wsv,
               float* __restrict__ out, int N)
{
    __shared__ float a_l[NATTR];
    __shared__ float s_l[NC];
    __shared__ float v_l[3][NC];
    __shared__ float ts[KSC];
    __shared__ float tv[3][KSC];

    const int n = blockIdx.x, t = threadIdx.x;

    if (t < NC) s_l[t] = fs[(size_t)n * NC + t];
    if (t >= 64 && t < 64 + NATTR) a_l[t - 64] = attrs[(size_t)n * NATTR + (t - 64)];
    for (int i = t; i < NC * 3; i += 256) {
        int c = i / 3, x = i - c * 3;
        v_l[x][c] = fv[(size_t)n * NC * 3 + i];
    }
    __syncthreads();

    for (int k = t; k < KSC; k += 256) {
        int c = k / NATTR, a = k - c * NATTR;
        float av = a_l[a];
        ts[k]    = s_l[c] * av;
        tv[0][k] = v_l[0][c] * av;
        tv[1][k] = v_l[1][c] * av;
        tv[2][k] = v_l[2][c] * av;
    }
    __syncthreads();

    const int wave = t >> 6, d = t & 63;
    const float inv_sc = 0.03952847075210474f;  // 1/sqrt(640)
    if (wave == 0) {
        float acc = 0.f;
        #pragma unroll 8
        for (int k = 0; k < KSC; k++) acc += ts[k] * Wss[k * NC + d];
        out[(size_t)N * 256 + (size_t)n * NC + d] = acc * inv_sc;
    } else {
        const int x = wave - 1;
        float acc = 0.f;
        #pragma unroll 8
        for (int k = 0; k < KSC; k++) acc += tv[x][k] * Wsv[k * NC + d];
        out[(size_t)N * 320 + (size_t)n * 192 + d * 3 + x] = acc * inv_sc;
    }
}

// ---------------------------------------------------------------------------
extern "C" void kernel_launch(void* const* d_in, const int* in_sizes, int n_in,
                              void* d_out, int out_size, void* d_ws, size_t ws_size,
                              hipStream_t stream)
{
    const float* attrs = (const float*)d_in[0];
    const float* fs    = (const float*)d_in[1];
    const float* fv    = (const float*)d_in[2];
    const float* sh0   = (const float*)d_in[3];
    const float* sh1   = (const float*)d_in[4];
    const float* ef    = (const float*)d_in[5];
    const int*   snd   = (const int*)d_in[6];
    const int*   rcv   = (const int*)d_in[7];
    const float* Wss   = (const float*)d_in[8];
    const float* Wsv   = (const float*)d_in[9];
    const float* Wes   = (const float*)d_in[10];
    const float* Wev   = (const float*)d_in[11];
    const float* W1    = (const float*)d_in[12];
    const float* W2    = (const float*)d_in[13];
    const float* W3    = (const float*)d_in[14];
    const float* W4    = (const float*)d_in[15];
    const float* Wos   = (const float*)d_in[16];
    const float* Wov   = (const float*)d_in[17];

    const int N = in_sizes[0] / NATTR;   // 50000
    const int E = in_sizes[6];           // 320000

    float* out = (float*)d_out;
    const float* s_st = out + (size_t)N * 256;  // self-linear s scratch (in d_out)
    const float* v_st = out + (size_t)N * 320;  // self-linear v scratch (in d_out)

    // receiver chunking so the f32 message buffer fits in ws_size
    size_t npc = ws_size / (MPN * sizeof(float));
    if (npc < 1) npc = 1;
    if (npc > (size_t)N) npc = N;
    float* m = (float*)d_ws;

    self_kernel<<<N, 256, 0, stream>>>(fs, fv, Wes, Wev, out, N);

    const int nb = (E + EPB - 1) / EPB;
    for (int r0 = 0; r0 < N; r0 += (int)npc) {
        int r1 = r0 + (int)npc; if (r1 > N) r1 = N;
        int cn = r1 - r0;
        hipMemsetAsync(m, 0, (size_t)cn * MPN * sizeof(float), stream);
        edge_kernel<<<nb, 256, 0, stream>>>(ef, sh0, sh1, snd, rcv,
                                            W1, W2, W3, W4, s_st, v_st,
                                            m, E, r0, r1);
        out_kernel<<<cn, 256, 0, stream>>>(m, Wos, Wov, out, N, r0);
    }

    sc_kernel<<<N, 256, 0, stream>>>(attrs, fs, fv, Wss, Wsv, out, N);
}